// Round 10
// baseline (76.949 us; speedup 1.0000x reference)
//
#include <hip/hip_runtime.h>
#include <hip/hip_bf16.h>
#include <math.h>

#define H_HEADS 16
#define DMODEL  1024
#define DHEAD   64
#define LSEQ    1024
#define CHUNK   64
#define NCHUNK  16
#define EPS_F   1e-6f

typedef __attribute__((ext_vector_type(8))) short bf16x8;   // 8 bf16 = 4 VGPRs
typedef __attribute__((ext_vector_type(4))) float f32x4;    // MFMA 16x16 accumulator

__device__ inline unsigned short f2bf(float f) {
    unsigned int u = __float_as_uint(f);
    u += 0x7FFF + ((u >> 16) & 1);          // round-to-nearest-even
    return (unsigned short)(u >> 16);
}
__device__ inline float bf2f(unsigned short h) {
    return __uint_as_float(((unsigned int)h) << 16);
}

// byte offset into a [64][64]-bf16 LDS tile (128B rows) with T2 XOR swizzle
__device__ inline int swz16(int row, int byteInRow) {
    return row * 128 + (byteInRow ^ ((row & 7) << 4));
}

// async global->LDS, 16B/lane. global src per-lane; LDS dst wave-uniform base.
#define GLOAD16(g, l) __builtin_amdgcn_global_load_lds( \
    (const __attribute__((address_space(1))) void*)(g), \
    (__attribute__((address_space(3))) void*)(l), 16, 0, 0)

// =====================================================================
// fp32 -> bf16 convert, WEIGHTS ONLY: Wq,Wk,Wv,Wo -> Wb[4][1M].
// grid = (1024, 4), 256 thr x float4.
// =====================================================================
__global__ __launch_bounds__(256)
void convertW_kernel(const float* __restrict__ Wq, const float* __restrict__ Wk,
                     const float* __restrict__ Wv, const float* __restrict__ Wo,
                     unsigned short* __restrict__ Wb)
{
    const int w = blockIdx.y;
    const float* src = (w == 0) ? Wq : (w == 1) ? Wk : (w == 2) ? Wv : Wo;
    unsigned short* dst = Wb + (size_t)w * (DMODEL * DMODEL);
    int idx = (blockIdx.x * 256 + threadIdx.x) * 4;
    float4 f = *(const float4*)(src + idx);
    *(ushort4*)(dst + idx) = make_ushort4(f2bf(f.x), f2bf(f.y), f2bf(f.z), f2bf(f.w));
}

// =====================================================================
// bf16 MFMA GEMM: BM=64, BN=128, BK=64, 4 waves (2x2 of 32x64), dbuf.
// PROJ:  A = fp32 X (q/k/v by z), reg-staged with inline fp32->bf16 cvt
//        (T14 split: loads before COMPUTE, cvt+ds_write after vmcnt(0));
//        epilogue scale+elu+1 (z<2), store bf16 [B,H,L,d].
// !PROJ: A = bf16 attb via global_load_lds; fp32 row-major store.
// B always bf16 via global_load_lds (inverse-swizzled source).
// =====================================================================
template<bool PROJ>
__global__ __launch_bounds__(256)
void mfma_gemm64_kernel(const float* __restrict__ Xq, const float* __restrict__ Xk,
                        const float* __restrict__ Xv,
                        const unsigned short* __restrict__ Ab,
                        const unsigned short* __restrict__ Wb,
                        unsigned short* __restrict__ qp,
                        unsigned short* __restrict__ kp,
                        unsigned short* __restrict__ vp,
                        float* __restrict__ outf)
{
    const int z = PROJ ? blockIdx.z : 0;
    const float* Xf = PROJ ? ((z == 0) ? Xq : (z == 1) ? Xk : Xv) : nullptr;
    const unsigned short* W = PROJ ? (Wb + (size_t)z * (DMODEL * DMODEL)) : Wb;

    __shared__ char AsB[2][8192];     // [dbuf][2 subtiles x 64 rows x 64B]
    __shared__ char BsB[2][16384];    // [dbuf][2 subtiles x 128 rows x 64B]

    const int tid  = threadIdx.x;
    const int m0   = blockIdx.y * 64;
    const int n0   = blockIdx.x * 128;
    const int lane = tid & 63;
    const int wid  = tid >> 6;
    const int wm   = (wid >> 1) * 32;
    const int wn   = (wid & 1) * 64;
    const int r16  = lane & 15;
    const int qh   = lane >> 4;

    // ---- B staging (gload_lds, inverse-swizzled source) ----
    const int rB0 = wid * 32 + (lane >> 2);
    const int sw  = ((lane & 3) ^ ((lane >> 3) & 3)) * 16;
    const char* srcB0 = (const char*)(W + (size_t)(n0 + rB0) * DMODEL) + sw;
    const char* srcB1 = (const char*)(W + (size_t)(n0 + rB0 + 16) * DMODEL) + sw;

    // ---- A staging ----
    // PROJ: reg-staged fp32. thread owns row arow, slot asb (8 elems/subtile)
    const int arow = tid >> 2;
    const int asb  = tid & 3;
    const int awr  = (asb ^ ((arow >> 1) & 3)) * 8;   // swizzled write slot (elems)
    const float* aSrc = PROJ ? (Xf + (size_t)(m0 + arow) * DMODEL + asb * 8) : nullptr;
    // !PROJ: gload_lds path (same as B)
    const int rA = wid * 16 + (lane >> 2);
    const char* srcA = PROJ ? nullptr : ((const char*)(Ab + (size_t)(m0 + rA) * DMODEL) + sw);

    // swizzled ds_read slot (elems)
    const int sl = (qh ^ ((r16 >> 1) & 3)) * 8;

    f32x4 acc[2][4];
#pragma unroll
    for (int i = 0; i < 2; ++i)
#pragma unroll
        for (int j = 0; j < 4; ++j) acc[i][j] = (f32x4)0.0f;

    float4 a0[2], a1[2];                       // PROJ in-flight A fp32
    auto A_LOAD = [&](int kt) {
#pragma unroll
        for (int hh = 0; hh < 2; ++hh) {
            a0[hh] = *(const float4*)(aSrc + kt + hh * 32);
            a1[hh] = *(const float4*)(aSrc + kt + hh * 32 + 4);
        }
    };
    auto A_WRITE = [&](int buf) {
#pragma unroll
        for (int hh = 0; hh < 2; ++hh) {
            bf16x8 pk;
            pk[0] = (short)f2bf(a0[hh].x); pk[1] = (short)f2bf(a0[hh].y);
            pk[2] = (short)f2bf(a0[hh].z); pk[3] = (short)f2bf(a0[hh].w);
            pk[4] = (short)f2bf(a1[hh].x); pk[5] = (short)f2bf(a1[hh].y);
            pk[6] = (short)f2bf(a1[hh].z); pk[7] = (short)f2bf(a1[hh].w);
            *(bf16x8*)(AsB[buf] + hh * 4096 + arow * 64 + awr * 2) = pk;
        }
    };
    auto STAGE_ISSUE = [&](int buf, int kt) {   // vmem issues only
        if (PROJ) A_LOAD(kt);
        else {
#pragma unroll
            for (int hh = 0; hh < 2; ++hh)
                GLOAD16(srcA + (size_t)(kt + hh * 32) * 2,
                        AsB[buf] + wid * 1024 + hh * 4096);
        }
#pragma unroll
        for (int hh = 0; hh < 2; ++hh) {
            size_t go = (size_t)(kt + hh * 32) * 2;
            GLOAD16(srcB0 + go, BsB[buf] + wid * 2048 + hh * 8192);
            GLOAD16(srcB1 + go, BsB[buf] + wid * 2048 + 1024 + hh * 8192);
        }
    };
    auto COMPUTE = [&](int buf) {
        bf16x8 af[2][2], bg[2][4];
#pragma unroll
        for (int hh = 0; hh < 2; ++hh) {
#pragma unroll
            for (int fm = 0; fm < 2; ++fm)
                af[hh][fm] = *(const bf16x8*)(AsB[buf] + hh * 4096 +
                                 ((wm + fm * 16 + r16) * 32 + sl) * 2);
#pragma unroll
            for (int fn = 0; fn < 4; ++fn)
                bg[hh][fn] = *(const bf16x8*)(BsB[buf] + hh * 8192 +
                                 ((wn + fn * 16 + r16) * 32 + sl) * 2);
        }
#pragma unroll
        for (int hh = 0; hh < 2; ++hh)
#pragma unroll
            for (int fm = 0; fm < 2; ++fm)
#pragma unroll
                for (int fn = 0; fn < 4; ++fn)
                    acc[fm][fn] = __builtin_amdgcn_mfma_f32_16x16x32_bf16(
                        af[hh][fm], bg[hh][fn], acc[fm][fn], 0, 0, 0);
    };

    // prologue
    STAGE_ISSUE(0, 0);
    asm volatile("s_waitcnt vmcnt(0)" ::: "memory");
    if (PROJ) A_WRITE(0);
    asm volatile("s_waitcnt lgkmcnt(0)" ::: "memory");
    __builtin_amdgcn_sched_barrier(0);
    __builtin_amdgcn_s_barrier();

    int cur = 0;
#pragma unroll 1
    for (int t = 0; t < (DMODEL / 64) - 1; ++t) {
        STAGE_ISSUE(cur ^ 1, (t + 1) * 64);    // issue next-tile vmem early
        __builtin_amdgcn_sched_barrier(0);
        COMPUTE(cur);                          // hide vmem latency here
        asm volatile("s_waitcnt vmcnt(0)" ::: "memory");
        if (PROJ) A_WRITE(cur ^ 1);            // land A into next buffer
        asm volatile("s_waitcnt lgkmcnt(0)" ::: "memory");
        __builtin_amdgcn_sched_barrier(0);
        __builtin_amdgcn_s_barrier();
        cur ^= 1;
    }
    COMPUTE(cur);                              // epilogue tile

    if (PROJ) {
        unsigned short* O = (z == 0) ? qp : (z == 1) ? kp : vp;
        const float sc = (z < 2) ? 0.125f : 1.f;
#pragma unroll
        for (int fm = 0; fm < 2; ++fm) {
#pragma unroll
            for (int r = 0; r < 4; ++r) {
                int m = m0 + wm + fm * 16 + qh * 4 + r;
                int b = m >> 10, l = m & 1023;
#pragma unroll
                for (int fn = 0; fn < 4; ++fn) {
                    int n = n0 + wn + fn * 16 + r16;
                    int h = n >> 6, e = n & 63;
                    float y = acc[fm][fn][r] * sc;
                    if (z < 2) y = (y > 0.f) ? y + 1.f : __expf(y);
                    O[(((size_t)(b * H_HEADS + h)) * LSEQ + l) * DHEAD + e] = f2bf(y);
                }
            }
        }
    } else {
#pragma unroll
        for (int fm = 0; fm < 2; ++fm) {
#pragma unroll
            for (int r = 0; r < 4; ++r) {
                int m = m0 + wm + fm * 16 + qh * 4 + r;
#pragma unroll
                for (int fn = 0; fn < 4; ++fn) {
                    int n = n0 + wn + fn * 16 + r16;
                    outf[(size_t)m * DMODEL + n] = acc[fm][fn][r];
                }
            }
        }
    }
}

// =====================================================================
// chunk KV sums via MFMA: St_c[e][i] = sum_s V[s][e]*K[s][i]  (fp32 out),
// z_c[i] = sum_s K[s][i] via ones-row MFMA on wave 0.
// =====================================================================
__global__ __launch_bounds__(256)
void chunk_kv_kernel(const unsigned short* __restrict__ kp,
                     const unsigned short* __restrict__ vp,
                     float* __restrict__ St, float* __restrict__ z)
{
    const int c = blockIdx.x, bh = blockIdx.y;
    const int tid = threadIdx.x;
    const int lane = tid & 63;
    const int w = tid >> 6;
    const int r16 = lane & 15, qh = lane >> 4;

    __shared__ unsigned short kT[64 * 64];   // K^T[i][s], swizzled
    __shared__ unsigned short vt[64 * 64];   // V^T[e][s], swizzled

    const size_t base = ((size_t)bh * LSEQ + (size_t)c * CHUNK) * DHEAD;

#pragma unroll
    for (int i = 0; i < 2; ++i) {
        int id  = tid + i * 256;
        int row = id >> 3;          // s
        int cg  = (id & 7) * 8;     // d/e octet
        bf16x8 kv = *(const bf16x8*)(kp + base + row * 64 + cg);
        bf16x8 vv = *(const bf16x8*)(vp + base + row * 64 + cg);
#pragma unroll
        for (int j = 0; j < 8; ++j) {
            *(unsigned short*)((char*)kT + swz16(cg + j, row * 2)) = (unsigned short)kv[j];
            *(unsigned short*)((char*)vt + swz16(cg + j, row * 2)) = (unsigned short)vv[j];
        }
    }
    __syncthreads();

    bf16x8 av[2], bK[2][4];
#pragma unroll
    for (int kk = 0; kk < 2; ++kk) {
        av[kk] = *(const bf16x8*)((char*)vt + swz16(w * 16 + r16, kk * 64 + qh * 16));
#pragma unroll
        for (int fn = 0; fn < 4; ++fn)
            bK[kk][fn] = *(const bf16x8*)((char*)kT + swz16(fn * 16 + r16, kk * 64 + qh * 16));
    }

    f32x4 acc[4];
#pragma unroll
    for (int fn = 0; fn < 4; ++fn) acc[fn] = (f32x4)0.0f;
#pragma unroll
    for (int kk = 0; kk < 2; ++kk)
#pragma unroll
        for (int fn = 0; fn < 4; ++fn)
            acc[fn] = __builtin_amdgcn_mfma_f32_16x16x32_bf16(av[kk], bK[kk][fn], acc[fn], 0, 0, 0);

    const size_t sbase = ((size_t)bh * NCHUNK + c) * (DHEAD * DHEAD);
#pragma unroll
    for (int r = 0; r < 4; ++r) {
        int e = w * 16 + qh * 4 + r;
#pragma unroll
        for (int fn = 0; fn < 4; ++fn)
            St[sbase + (size_t)e * 64 + fn * 16 + r16] = acc[fn][r];
    }

    if (w == 0) {   // z via ones-row MFMA (A = all 1.0 bf16, exact)
        bf16x8 ones;
#pragma unroll
        for (int j = 0; j < 8; ++j) ones[j] = (short)0x3F80;
        f32x4 accz[4];
#pragma unroll
        for (int fn = 0; fn < 4; ++fn) accz[fn] = (f32x4)0.0f;
#pragma unroll
        for (int kk = 0; kk < 2; ++kk)
#pragma unroll
            for (int fn = 0; fn < 4; ++fn)
                accz[fn] = __builtin_amdgcn_mfma_f32_16x16x32_bf16(ones, bK[kk][fn], accz[fn], 0, 0, 0);
        if (qh == 0) {
            const size_t zb = ((size_t)bh * NCHUNK + c) * 64;
#pragma unroll
            for (int fn = 0; fn < 4; ++fn)
                z[zb + fn * 16 + r16] = accz[fn][0];
        }
    }
}

// =====================================================================
// Exclusive prefix over chunks: St fp32 -> stb bf16 (pre-swizzled rows so
// attn can global_load_lds linearly); z scanned fp32 in place.
// =====================================================================
__global__ __launch_bounds__(256)
void prefix_kernel(const float* __restrict__ St, unsigned short* __restrict__ stb,
                   float* __restrict__ z)
{
    const int bh   = blockIdx.x >> 4;
    const int eblk = blockIdx.x & 15;
    const int idx  = eblk * 256 + threadIdx.x;   // 0..4095
    const int e = idx >> 6, i = idx & 63;

    const size_t ibase = (size_t)bh * NCHUNK * 4096 + idx;
    float v[NCHUNK];
#pragma unroll
    for (int c = 0; c < NCHUNK; ++c)
        v[c] = St[ibase + (size_t)c * 4096];

    const size_t obase = (size_t)bh * NCHUNK * 4096 + e * 64 + (i ^ ((e & 7) << 3));
    float run = 0.f;
#pragma unroll
    for (int c = 0; c < NCHUNK; ++c) {
        stb[obase + (size_t)c * 4096] = f2bf(run);
        run += v[c];
    }

    if (eblk == 0 && threadIdx.x < DHEAD) {
        const size_t zb = (size_t)bh * NCHUNK * DHEAD + threadIdx.x;
        float zv[NCHUNK];
#pragma unroll
        for (int c = 0; c < NCHUNK; ++c)
            zv[c] = z[zb + (size_t)c * DHEAD];
        float zr = 0.f;
#pragma unroll
        for (int c = 0; c < NCHUNK; ++c) {
            z[zb + (size_t)c * DHEAD] = zr;
            zr += zv[c];
        }
    }
}

// =====================================================================
// Per-chunk causal attention, full MFMA:
//   P = Qp@Kp^T (mask, rowsum in C-regs) ; O = Qp@Sprev^T + P@V^T.
//   den = qp.z_prev (pre-pass) + rowsum.  grid = (NC, BH), 256 thr.
// =====================================================================
__global__ __launch_bounds__(256)
void attn_mfma_kernel(const unsigned short* __restrict__ qp,
                      const unsigned short* __restrict__ kp,
                      const unsigned short* __restrict__ vp,
                      const unsigned short* __restrict__ stb,
                      const float* __restrict__ zpre,
                      unsigned short* __restrict__ att)
{
    const int c = blockIdx.x, bh = blockIdx.y;
    const int b = bh >> 4, h = bh & 15;
    const int tid = threadIdx.x;
    const int lane = tid & 63;
    const int w = tid >> 6;
    const int r16 = lane & 15, qh = lane >> 4;

    __shared__ unsigned short qs[64 * 64];   // Qp[t][d] swizzled
    __shared__ unsigned short ks[64 * 64];   // Kp[s][d] swizzled
    __shared__ unsigned short vt[64 * 64];   // V^T[e][s] swizzled
    __shared__ unsigned short stl[64 * 64];  // Sprev^T[e][i] (global pre-swizzled)
    __shared__ unsigned short ps[64 * 64];   // masked P[t][s] swizzled
    __shared__ float denl[64];

    const size_t base = ((size_t)bh * LSEQ + (size_t)c * CHUNK) * DHEAD;
    const unsigned short* stg = stb + ((size_t)bh * NCHUNK + c) * 4096;
    const float* zp = zpre + ((size_t)bh * NCHUNK + c) * 64;

    // stage Sprev^T via gload (global rows pre-swizzled by prefix_kernel)
    {
        const char* src = (const char*)stg + w * 2048 + lane * 16;
        GLOAD16(src,        (char*)stl + w * 2048);
        GLOAD16(src + 1024, (char*)stl + w * 2048 + 1024);
    }
    // stage Qp, Kp natural; V transposed
#pragma unroll
    for (int i = 0; i < 2; ++i) {
        int id  = tid + i * 256;
        int row = id >> 3;
        int cg  = (id & 7) * 8;
        bf16x8 qv = *(const bf16x8*)(qp + base + row * 64 + cg);
        bf16x8 kv = *(const bf16x8*)(kp + base + row * 64 + cg);
        *(bf16x8*)((char*)qs + swz16(row, cg * 2)) = qv;
        *(bf16x8*)((char*)ks + swz16(row, cg * 2)) = kv;
        bf16x8 vv = *(const bf16x8*)(vp + base + row * 64 + cg);
#pragma unroll
        for (int j = 0; j < 8; ++j)
            *(unsigned short*)((char*)vt + swz16(cg + j, row * 2)) = (unsigned short)vv[j];
    }
    // den1[t] = qp_row_t . z_prev  (4 lanes per row)
    {
        int t = tid >> 2, kq = tid & 3;
        const unsigned short* qrow = qp + base + t * 64 + kq * 16;
        bf16x8 a0 = *(const bf16x8*)(qrow);
        bf16x8 a1 = *(const bf16x8*)(qrow + 8);
        float s = 0.f;
#pragma unroll
        for (int j = 0; j < 8; ++j) {
            s = fmaf(bf2f((unsigned short)a0[j]), zp[kq * 16 + j], s);
            s = fmaf(bf2f((unsigned short)a1[j]), zp[kq * 16 + 8 + j], s);
        }
        s += __shfl_xor(s, 1);
        s += __shfl_xor(s, 2);
        if (kq == 0) denl[t] = s;
    }
    __syncthreads();   // drains gload (vmcnt) + all LDS staging

    // A-frags of Qp for wave's 16-row slice (shared by P and O1)
    bf16x8 aq[2];
#pragma unroll
    for (int kk = 0; kk < 2; ++kk)
        aq[kk] = *(const bf16x8*)((char*)qs + swz16(w * 16 + r16, kk * 64 + qh * 16));

    // ---- P = Qp @ Kp^T ----
    f32x4 accp[4];
#pragma unroll
    for (int fn = 0; fn < 4; ++fn) accp[fn] = (f32x4)0.0f;
#pragma unroll
    for (int kk = 0; kk < 2; ++kk)
#pragma unroll
        for (int fn = 0; fn < 4; ++fn) {
            bf16x8 bk = *(const bf16x8*)((char*)ks + swz16(fn * 16 + r16, kk * 64 + qh * 16));
            accp[fn] = __builtin_amdgcn_mfma_f32_16x16x32_bf16(aq[kk], bk, accp[fn], 0, 0, 0);
        }

    // mask (causal within chunk), rowsum, write bf16 P to LDS
    float rs[4];
#pragma unroll
    for (int r = 0; r < 4; ++r) {
        int t_loc = w * 16 + qh * 4 + r;
        float rsum = 0.f;
#pragma unroll
        for (int fn = 0; fn < 4; ++fn) {
            int s_loc = fn * 16 + r16;
            float p = (s_loc <= t_loc) ? accp[fn][r] : 0.f;
            rsum += p;
            *(unsigned short*)((char*)ps + swz16(t_loc, s_loc * 2)) = f2bf(p);
        }
        rsum += __shfl_xor(rsum, 1);
        rsum += __shfl_xor(rsum, 2);
        rsum += __shfl_xor(rsum, 4);
        rsum += __shfl_xor(rsum, 8);
        rs[r] = rsum;
    }

    // ---- O = Qp @ Sprev^T + P @ V^T ----
    f32x4 acc[4];
#pragma unroll
    for (int fn = 0; fn < 4; ++fn) acc[fn] = (f32x4)0.0f;
#pragma unroll
    for (int kk = 0; kk < 2; ++kk)
#pragma unroll
        for (int fn = 0; fn < 4; ++fn) {
            bf16x8 bs = *(const bf16x8*)((char*)stl + swz16(fn * 16 + r16, kk * 64 + qh * 16));
            acc[fn] = __builtin_amdgcn_mfma_f32_16x16x32_bf16(aq[kk], bs, acc[fn], 0, 0, 0);
        }
    bf16x8 ap[2];
#pragma unroll
    for (int kk = 0; kk < 2; ++kk)
        ap[kk] = *(const bf16x8*)((char*)ps + swz16(w * 16 + r16, kk * 64 + qh * 16));
#pragma unroll
    for (int kk = 0; kk < 2; ++kk)
#pragma unroll
        for (int fn = 0; fn < 4; ++fn) {
            bf16x8 bv = *(const bf16x8*)((char*)vt + swz16(fn * 16 + r16, kk * 64 + qh * 16));
            acc[fn] = __builtin_amdgcn_mfma_f32_16x16x32_bf16(ap[kk], bv, acc[fn], 0, 0, 0);
        }

    // epilogue: divide by den, store bf16 att [B, L, D]
#pragma unroll
    for (int r = 0; r < 4; ++r) {
        int t_loc = w * 16 + qh * 4 + r;
        int l = c * CHUNK + t_loc;
        float inv = 1.f / (denl[t_loc] + rs[r] + EPS_F);
#pragma unroll
        for (int fn = 0; fn < 4; ++fn) {
            int e = fn * 16 + r16;
            att[((size_t)b * LSEQ + l) * DMODEL + h * DHEAD + e] = f2bf(acc[fn][r] * inv);
        }
    }
}

// =====================================================================
extern "C" void kernel_launch(void* const* d_in, const int* in_sizes, int n_in,
                              void* d_out, int out_size, void* d_ws, size_t ws_size,
                              hipStream_t stream)
{
    const float* query = (const float*)d_in[0];
    const float* key_  = (const float*)d_in[1];
    const float* value = (const float*)d_in[2];
    const float* Wq = (const float*)d_in[3];
    const float* Wk = (const float*)d_in[4];
    const float* Wv = (const float*)d_in[5];
    const float* Wo = (const float*)d_in[6];
    float* out = (float*)d_out;

    const int M  = 2 * LSEQ;     // 2048
    const int BH = 2 * H_HEADS;  // 32

    // ws layout (bytes):
    //   [0,        8.4M)   Wb   : bf16 Wq|Wk|Wv|Wo
    //   [8.4M,    21.0M)   qp,kp,vp : bf16 [B,H,L,d]
    //   [21.0M,   25.2M)   attb : bf16 [M,1024]
    //   [25.2M,   33.55M)  St   : fp32 S^T chunk sums
    //   [33.55M,  33.69M)  z    : fp32
    //   [33.69M,  37.88M)  stb  : bf16 S_prev^T pre-swizzled
    char* wsb = (char*)d_ws;
    unsigned short* Wb   = (unsigned short*)(wsb);
    unsigned short* qp   = (unsigned short*)(wsb + 8388608);
    unsigned short* kp   = (unsigned short*)(wsb + 12582912);
    unsigned short* vp   = (unsigned short*)(wsb + 16777216);
    unsigned short* attb = (unsigned short*)(wsb + 20971520);
    float*          St   = (float*)(wsb + 25165824);
    float*          z    = (float*)(wsb + 33554432);
    unsigned short* stb  = (unsigned short*)(wsb + 33685504);

    dim3 blk(256);
    convertW_kernel<<<dim3(DMODEL * DMODEL / 1024, 4), blk, 0, stream>>>(
        Wq, Wk, Wv, Wo, Wb);
    mfma_gemm64_kernel<true><<<dim3(DMODEL / 128, M / 64, 3), blk, 0, stream>>>(
        query, key_, value, nullptr, Wb, qp, kp, vp, nullptr);
    chunk_kv_kernel<<<dim3(NCHUNK, BH), blk, 0, stream>>>(kp, vp, St, z);
    prefix_kernel<<<dim3(BH * 16), blk, 0, stream>>>(St, stb, z);
    attn_mfma_kernel<<<dim3(NCHUNK, BH), blk, 0, stream>>>(qp, kp, vp, stb, z, attb);
    mfma_gemm64_kernel<false><<<dim3(DMODEL / 128, M / 64, 1), blk, 0, stream>>>(
        nullptr, nullptr, nullptr, attb, Wb + 3 * (size_t)DMODEL * DMODEL,
        nullptr, nullptr, nullptr, out);
}

// Round 11
// 76.487 us; speedup vs baseline: 1.0060x; 1.0060x over previous
//
#include <hip/hip_runtime.h>
#include <hip/hip_bf16.h>
#include <math.h>

#define H_HEADS 16
#define DMODEL  1024
#define DHEAD   64
#define LSEQ    1024
#define CHUNK   64
#define NCHUNK  16
#define EPS_F   1e-6f

typedef __attribute__((ext_vector_type(8))) short bf16x8;   // 8 bf16 = 4 VGPRs
typedef __attribute__((ext_vector_type(4))) float f32x4;    // MFMA 16x16 accumulator

__device__ inline unsigned short f2bf(float f) {
    unsigned int u = __float_as_uint(f);
    u += 0x7FFF + ((u >> 16) & 1);          // round-to-nearest-even
    return (unsigned short)(u >> 16);
}
__device__ inline float bf2f(unsigned short h) {
    return __uint_as_float(((unsigned int)h) << 16);
}

// byte offset into a [64][64]-bf16 LDS tile (128B rows) with T2 XOR swizzle
__device__ inline int swz16(int row, int byteInRow) {
    return row * 128 + (byteInRow ^ ((row & 7) << 4));
}

// async global->LDS, 16B/lane. global src per-lane; LDS dst wave-uniform base.
#define GLOAD16(g, l) __builtin_amdgcn_global_load_lds( \
    (const __attribute__((address_space(1))) void*)(g), \
    (__attribute__((address_space(3))) void*)(l), 16, 0, 0)

// =====================================================================
// fp32 -> bf16 convert: q,k,v -> Xb[3][2M]; Wq,Wk,Wv,Wo -> Wb[4][1M].
// =====================================================================
__global__ __launch_bounds__(256)
void convert_kernel(const float* __restrict__ q, const float* __restrict__ k,
                    const float* __restrict__ v,
                    const float* __restrict__ Wq, const float* __restrict__ Wk,
                    const float* __restrict__ Wv, const float* __restrict__ Wo,
                    unsigned short* __restrict__ Xb, unsigned short* __restrict__ Wb)
{
    const int y = blockIdx.y;
    const float* src;
    unsigned short* dst;
    int n;
    if (y < 3) {
        src = (y == 0) ? q : (y == 1) ? k : v;
        dst = Xb + (size_t)y * (2 * LSEQ * DMODEL);
        n = 2 * LSEQ * DMODEL;
    } else {
        int w = y - 3;
        src = (w == 0) ? Wq : (w == 1) ? Wk : (w == 2) ? Wv : Wo;
        dst = Wb + (size_t)w * (DMODEL * DMODEL);
        n = DMODEL * DMODEL;
    }
    int idx = (blockIdx.x * 256 + threadIdx.x) * 4;
    if (idx < n) {
        float4 f = *(const float4*)(src + idx);
        ushort4 h = make_ushort4(f2bf(f.x), f2bf(f.y), f2bf(f.z), f2bf(f.w));
        *(ushort4*)(dst + idx) = h;
    }
}

// =====================================================================
// bf16 MFMA GEMM: BM=64, BN=128, BK=64, 4 waves (2x2 of 32x64), dbuf,
// global_load_lds staging (inverse-swizzled source, swizzled ds_read).
// FLAT 1D grid with XCD-chunked decode: all m-blocks sharing a (z,n0)
// B-panel land on one XCD -> B-panel served from that XCD's L2.
//   PROJ:  grid=768. xcd=bid&7 owns column-groups [3*xcd, 3*xcd+2];
//          cg -> (n0 = (cg&7)*128, z = cg>>3); m0 = (bid>>3 % 32)*64.
//   !PROJ: grid=256. n0 = (bid&7)*128, m0 = (bid>>3)*64.
// =====================================================================
template<bool PROJ>
__global__ __launch_bounds__(256)
void mfma_gemm64_kernel(const unsigned short* __restrict__ Xb,
                        const unsigned short* __restrict__ Wb,
                        unsigned short* __restrict__ qp,
                        unsigned short* __restrict__ kp,
                        unsigned short* __restrict__ vp,
                        float* __restrict__ outf)
{
    const int bid = blockIdx.x;
    const int xcd = bid & 7;
    const int idx = bid >> 3;                  // 0..95 (PROJ) / 0..31
    const int cg  = PROJ ? (xcd * 3 + (idx >> 5)) : xcd;
    const int z   = PROJ ? (cg >> 3) : 0;
    const int n0  = (cg & 7) * 128;
    const int m0  = (PROJ ? (idx & 31) : idx) * 64;

    const unsigned short* A = PROJ ? (Xb + (size_t)z * (2 * LSEQ * DMODEL)) : Xb;
    const unsigned short* W = PROJ ? (Wb + (size_t)z * (DMODEL * DMODEL)) : Wb;

    __shared__ char AsB[2][8192];     // [dbuf][2 subtiles x 64 rows x 64B]
    __shared__ char BsB[2][16384];    // [dbuf][2 subtiles x 128 rows x 64B]

    const int tid  = threadIdx.x;
    const int lane = tid & 63;
    const int wid  = tid >> 6;
    const int wm   = (wid >> 1) * 32;
    const int wn   = (wid & 1) * 64;
    const int r16  = lane & 15;
    const int qh   = lane >> 4;

    // staging: wave wid owns 1KB of A and 2KB of B per subtile
    const int rA  = wid * 16 + (lane >> 2);
    const int rB0 = wid * 32 + (lane >> 2);
    const int sw  = ((lane & 3) ^ ((lane >> 3) & 3)) * 16;   // inverse slot swizzle
    const char* srcA  = (const char*)(A + (size_t)(m0 + rA)  * DMODEL) + sw;
    const char* srcB0 = (const char*)(W + (size_t)(n0 + rB0) * DMODEL) + sw;
    const char* srcB1 = (const char*)(W + (size_t)(n0 + rB0 + 16) * DMODEL) + sw;

    const int sl = (qh ^ ((r16 >> 1) & 3)) * 8;   // swizzled ds_read slot

    f32x4 acc[2][4];
#pragma unroll
    for (int i = 0; i < 2; ++i)
#pragma unroll
        for (int j = 0; j < 4; ++j) acc[i][j] = (f32x4)0.0f;

    auto STAGE = [&](int buf, int kt) {
#pragma unroll
        for (int hh = 0; hh < 2; ++hh) {
            size_t go = (size_t)(kt + hh * 32) * 2;
            GLOAD16(srcA  + go, AsB[buf] + wid * 1024 + hh * 4096);
            GLOAD16(srcB0 + go, BsB[buf] + wid * 2048 + hh * 8192);
            GLOAD16(srcB1 + go, BsB[buf] + wid * 2048 + 1024 + hh * 8192);
        }
    };
    auto COMPUTE = [&](int buf) {
        bf16x8 af[2][2], bg[2][4];
#pragma unroll
        for (int hh = 0; hh < 2; ++hh) {
#pragma unroll
            for (int fm = 0; fm < 2; ++fm)
                af[hh][fm] = *(const bf16x8*)(AsB[buf] + hh * 4096 +
                                 ((wm + fm * 16 + r16) * 32 + sl) * 2);
#pragma unroll
            for (int fn = 0; fn < 4; ++fn)
                bg[hh][fn] = *(const bf16x8*)(BsB[buf] + hh * 8192 +
                                 ((wn + fn * 16 + r16) * 32 + sl) * 2);
        }
#pragma unroll
        for (int hh = 0; hh < 2; ++hh)
#pragma unroll
            for (int fm = 0; fm < 2; ++fm)
#pragma unroll
                for (int fn = 0; fn < 4; ++fn)
                    acc[fm][fn] = __builtin_amdgcn_mfma_f32_16x16x32_bf16(
                        af[hh][fm], bg[hh][fn], acc[fm][fn], 0, 0, 0);
    };

    // prologue
    STAGE(0, 0);
    asm volatile("s_waitcnt vmcnt(0)" ::: "memory");
    __builtin_amdgcn_s_barrier();

    int cur = 0;
#pragma unroll 1
    for (int t = 0; t < (DMODEL / 64) - 1; ++t) {
        STAGE(cur ^ 1, (t + 1) * 64);          // prefetch next tile
        __builtin_amdgcn_sched_barrier(0);
        COMPUTE(cur);                          // hide load latency here
        asm volatile("s_waitcnt vmcnt(0) lgkmcnt(0)" ::: "memory");
        __builtin_amdgcn_sched_barrier(0);
        __builtin_amdgcn_s_barrier();
        cur ^= 1;
    }
    COMPUTE(cur);                              // epilogue tile

    if (PROJ) {
        unsigned short* O = (z == 0) ? qp : (z == 1) ? kp : vp;
        const float sc = (z < 2) ? 0.125f : 1.f;
#pragma unroll
        for (int fm = 0; fm < 2; ++fm) {
#pragma unroll
            for (int r = 0; r < 4; ++r) {
                int m = m0 + wm + fm * 16 + qh * 4 + r;
                int b = m >> 10, l = m & 1023;
#pragma unroll
                for (int fn = 0; fn < 4; ++fn) {
                    int n = n0 + wn + fn * 16 + r16;
                    int h = n >> 6, e = n & 63;
                    float y = acc[fm][fn][r] * sc;
                    if (z < 2) y = (y > 0.f) ? y + 1.f : __expf(y);
                    O[(((size_t)(b * H_HEADS + h)) * LSEQ + l) * DHEAD + e] = f2bf(y);
                }
            }
        }
    } else {
#pragma unroll
        for (int fm = 0; fm < 2; ++fm) {
#pragma unroll
            for (int r = 0; r < 4; ++r) {
                int m = m0 + wm + fm * 16 + qh * 4 + r;
#pragma unroll
                for (int fn = 0; fn < 4; ++fn) {
                    int n = n0 + wn + fn * 16 + r16;
                    outf[(size_t)m * DMODEL + n] = acc[fm][fn][r];
                }
            }
        }
    }
}

// =====================================================================
// chunk KV sums via MFMA: St_c[e][i] = sum_s V[s][e]*K[s][i]  (fp32 out),
// z_c[i] = sum_s K[s][i] via ones-row MFMA on wave 0.
// =====================================================================
__global__ __launch_bounds__(256)
void chunk_kv_kernel(const unsigned short* __restrict__ kp,
                     const unsigned short* __restrict__ vp,
                     float* __restrict__ St, float* __restrict__ z)
{
    const int c = blockIdx.x, bh = blockIdx.y;
    const int tid = threadIdx.x;
    const int lane = tid & 63;
    const int w = tid >> 6;
    const int r16 = lane & 15, qh = lane >> 4;

    __shared__ unsigned short kT[64 * 64];   // K^T[i][s], swizzled
    __shared__ unsigned short vt[64 * 64];   // V^T[e][s], swizzled

    const size_t base = ((size_t)bh * LSEQ + (size_t)c * CHUNK) * DHEAD;

#pragma unroll
    for (int i = 0; i < 2; ++i) {
        int id  = tid + i * 256;
        int row = id >> 3;          // s
        int cg  = (id & 7) * 8;     // d/e octet
        bf16x8 kv = *(const bf16x8*)(kp + base + row * 64 + cg);
        bf16x8 vv = *(const bf16x8*)(vp + base + row * 64 + cg);
#pragma unroll
        for (int j = 0; j < 8; ++j) {
            *(unsigned short*)((char*)kT + swz16(cg + j, row * 2)) = (unsigned short)kv[j];
            *(unsigned short*)((char*)vt + swz16(cg + j, row * 2)) = (unsigned short)vv[j];
        }
    }
    __syncthreads();

    bf16x8 av[2], bK[2][4];
#pragma unroll
    for (int kk = 0; kk < 2; ++kk) {
        av[kk] = *(const bf16x8*)((char*)vt + swz16(w * 16 + r16, kk * 64 + qh * 16));
#pragma unroll
        for (int fn = 0; fn < 4; ++fn)
            bK[kk][fn] = *(const bf16x8*)((char*)kT + swz16(fn * 16 + r16, kk * 64 + qh * 16));
    }

    f32x4 acc[4];
#pragma unroll
    for (int fn = 0; fn < 4; ++fn) acc[fn] = (f32x4)0.0f;
#pragma unroll
    for (int kk = 0; kk < 2; ++kk)
#pragma unroll
        for (int fn = 0; fn < 4; ++fn)
            acc[fn] = __builtin_amdgcn_mfma_f32_16x16x32_bf16(av[kk], bK[kk][fn], acc[fn], 0, 0, 0);

    const size_t sbase = ((size_t)bh * NCHUNK + c) * (DHEAD * DHEAD);
#pragma unroll
    for (int r = 0; r < 4; ++r) {
        int e = w * 16 + qh * 4 + r;
#pragma unroll
        for (int fn = 0; fn < 4; ++fn)
            St[sbase + (size_t)e * 64 + fn * 16 + r16] = acc[fn][r];
    }

    if (w == 0) {   // z via ones-row MFMA (A = all 1.0 bf16, exact)
        bf16x8 ones;
#pragma unroll
        for (int j = 0; j < 8; ++j) ones[j] = (short)0x3F80;
        f32x4 accz[4];
#pragma unroll
        for (int fn = 0; fn < 4; ++fn) accz[fn] = (f32x4)0.0f;
#pragma unroll
        for (int kk = 0; kk < 2; ++kk)
#pragma unroll
            for (int fn = 0; fn < 4; ++fn)
                accz[fn] = __builtin_amdgcn_mfma_f32_16x16x32_bf16(ones, bK[kk][fn], accz[fn], 0, 0, 0);
        if (qh == 0) {
            const size_t zb = ((size_t)bh * NCHUNK + c) * 64;
#pragma unroll
            for (int fn = 0; fn < 4; ++fn)
                z[zb + fn * 16 + r16] = accz[fn][0];
        }
    }
}

// =====================================================================
// Exclusive prefix over chunks: St fp32 -> stb bf16 (pre-swizzled rows so
// attn can global_load_lds linearly); z scanned fp32 in place.
// =====================================================================
__global__ __launch_bounds__(256)
void prefix_kernel(const float* __restrict__ St, unsigned short* __restrict__ stb,
                   float* __restrict__ z)
{
    const int bh   = blockIdx.x >> 4;
    const int eblk = blockIdx.x & 15;
    const int idx  = eblk * 256 + threadIdx.x;   // 0..4095
    const int e = idx >> 6, i = idx & 63;

    const size_t ibase = (size_t)bh * NCHUNK * 4096 + idx;
    float v[NCHUNK];
#pragma unroll
    for (int c = 0; c < NCHUNK; ++c)
        v[c] = St[ibase + (size_t)c * 4096];

    const size_t obase = (size_t)bh * NCHUNK * 4096 + e * 64 + (i ^ ((e & 7) << 3));
    float run = 0.f;
#pragma unroll
    for (int c = 0; c < NCHUNK; ++c) {
        stb[obase + (size_t)c * 4096] = f2bf(run);
        run += v[c];
    }

    if (eblk == 0 && threadIdx.x < DHEAD) {
        const size_t zb = (size_t)bh * NCHUNK * DHEAD + threadIdx.x;
        float zv[NCHUNK];
#pragma unroll
        for (int c = 0; c < NCHUNK; ++c)
            zv[c] = z[zb + (size_t)c * DHEAD];
        float zr = 0.f;
#pragma unroll
        for (int c = 0; c < NCHUNK; ++c) {
            z[zb + (size_t)c * DHEAD] = zr;
            zr += zv[c];
        }
    }
}

// =====================================================================
// Per-chunk causal attention, full MFMA:
//   P = Qp@Kp^T (mask, rowsum in C-regs) ; O = Qp@Sprev^T + P@V^T.
//   den = qp.z_prev (pre-pass) + rowsum.  grid = (NC, BH), 256 thr.
// =====================================================================
__global__ __launch_bounds__(256)
void attn_mfma_kernel(const unsigned short* __restrict__ qp,
                      const unsigned short* __restrict__ kp,
                      const unsigned short* __restrict__ vp,
                      const unsigned short* __restrict__ stb,
                      const float* __restrict__ zpre,
                      unsigned short* __restrict__ att)
{
    const int c = blockIdx.x, bh = blockIdx.y;
    const int b = bh >> 4, h = bh & 15;
    const int tid = threadIdx.x;
    const int lane = tid & 63;
    const int w = tid >> 6;
    const int r16 = lane & 15, qh = lane >> 4;

    __shared__ unsigned short qs[64 * 64];   // Qp[t][d] swizzled
    __shared__ unsigned short ks[64 * 64];   // Kp[s][d] swizzled
    __shared__ unsigned short vt[64 * 64];   // V^T[e][s] swizzled
    __shared__ unsigned short stl[64 * 64];  // Sprev^T[e][i] (global pre-swizzled)
    __shared__ unsigned short ps[64 * 64];   // masked P[t][s] swizzled
    __shared__ float denl[64];

    const size_t base = ((size_t)bh * LSEQ + (size_t)c * CHUNK) * DHEAD;
    const unsigned short* stg = stb + ((size_t)bh * NCHUNK + c) * 4096;
    const float* zp = zpre + ((size_t)bh * NCHUNK + c) * 64;

    // stage Sprev^T via gload (global rows pre-swizzled by prefix_kernel)
    {
        const char* src = (const char*)stg + w * 2048 + lane * 16;
        GLOAD16(src,        (char*)stl + w * 2048);
        GLOAD16(src + 1024, (char*)stl + w * 2048 + 1024);
    }
    // stage Qp, Kp natural; V transposed
#pragma unroll
    for (int i = 0; i < 2; ++i) {
        int id  = tid + i * 256;
        int row = id >> 3;
        int cg  = (id & 7) * 8;
        bf16x8 qv = *(const bf16x8*)(qp + base + row * 64 + cg);
        bf16x8 kv = *(const bf16x8*)(kp + base + row * 64 + cg);
        *(bf16x8*)((char*)qs + swz16(row, cg * 2)) = qv;
        *(bf16x8*)((char*)ks + swz16(row, cg * 2)) = kv;
        bf16x8 vv = *(const bf16x8*)(vp + base + row * 64 + cg);
#pragma unroll
        for (int j = 0; j < 8; ++j)
            *(unsigned short*)((char*)vt + swz16(cg + j, row * 2)) = (unsigned short)vv[j];
    }
    // den1[t] = qp_row_t . z_prev  (4 lanes per row)
    {
        int t = tid >> 2, kq = tid & 3;
        const unsigned short* qrow = qp + base + t * 64 + kq * 16;
        bf16x8 a0 = *(const bf16x8*)(qrow);
        bf16x8 a1 = *(const bf16x8*)(qrow + 8);
        float s = 0.f;
#pragma unroll
        for (int j = 0; j < 8; ++j) {
            s = fmaf(bf2f((unsigned short)a0[j]), zp[kq * 16 + j], s);
            s = fmaf(bf2f((unsigned short)a1[j]), zp[kq * 16 + 8 + j], s);
        }
        s += __shfl_xor(s, 1);
        s += __shfl_xor(s, 2);
        if (kq == 0) denl[t] = s;
    }
    __syncthreads();   // drains gload (vmcnt) + all LDS staging

    // A-frags of Qp for wave's 16-row slice (shared by P and O1)
    bf16x8 aq[2];
#pragma unroll
    for (int kk = 0; kk < 2; ++kk)
        aq[kk] = *(const bf16x8*)((char*)qs + swz16(w * 16 + r16, kk * 64 + qh * 16));

    // ---- P = Qp @ Kp^T ----
    f32x4 accp[4];
#pragma unroll
    for (int fn = 0; fn < 4; ++fn) accp[fn] = (f32x4)0.0f;
#pragma unroll
    for (int kk = 0; kk < 2; ++kk)
#pragma unroll
        for (int fn = 0; fn < 4; ++fn) {
            bf16x8 bk = *(const bf16x8*)((char*)ks + swz16(fn * 16 + r16, kk * 64 + qh * 16));
            accp[fn] = __builtin_amdgcn_mfma_f32_16x16x32_bf16(aq[kk], bk, accp[fn], 0, 0, 0);
        }

    // mask (causal within chunk), rowsum, write bf16 P to LDS
    float rs[4];
#pragma unroll
    for (int r = 0; r < 4; ++r) {
        int t_loc = w * 16 + qh * 4 + r;
        float rsum = 0.f;
#pragma unroll
        for (int fn = 0; fn < 4; ++fn) {
            int s_loc = fn * 16 + r16;
            float p = (s_loc <= t_loc) ? accp[fn][r] : 0.f;
            rsum += p;
            *(unsigned short*)((char*)ps + swz16(t_loc, s_loc * 2)) = f2bf(p);
        }
        rsum += __shfl_xor(rsum, 1);
        rsum += __shfl_xor(rsum, 2);
        rsum += __shfl_xor(rsum, 4);
        rsum += __shfl_xor(rsum, 8);
        rs[r] = rsum;
    }

    // ---- O = Qp @ Sprev^T + P @ V^T ----
    f32x4 acc[4];
#pragma unroll
    for (int fn = 0; fn < 4; ++fn) acc[fn] = (f32x4)0.0f;
#pragma unroll
    for (int kk = 0; kk < 2; ++kk)
#pragma unroll
        for (int fn = 0; fn < 4; ++fn) {
            bf16x8 bs = *(const bf16x8*)((char*)stl + swz16(fn * 16 + r16, kk * 64 + qh * 16));
            acc[fn] = __builtin_amdgcn_mfma_f32_16x16x32_bf16(aq[kk], bs, acc[fn], 0, 0, 0);
        }
    bf16x8 ap[2];
#pragma unroll
    for (int kk = 0; kk < 2; ++kk)
        ap[kk] = *(const bf16x8*)((char*)ps + swz16(w * 16 + r16, kk * 64 + qh * 16));
#pragma unroll
    for (int kk = 0; kk < 2; ++kk)
#pragma unroll
        for (int fn = 0; fn < 4; ++fn) {
            bf16x8 bv = *(const bf16x8*)((char*)vt + swz16(fn * 16 + r16, kk * 64 + qh * 16));
            acc[fn] = __builtin_amdgcn_mfma_f32_16x16x32_bf16(ap[kk], bv, acc[fn], 0, 0, 0);
        }

    // epilogue: divide by den, store bf16 att [B, L, D]
#pragma unroll
    for (int r = 0; r < 4; ++r) {
        int t_loc = w * 16 + qh * 4 + r;
        int l = c * CHUNK + t_loc;
        float inv = 1.f / (denl[t_loc] + rs[r] + EPS_F);
#pragma unroll
        for (int fn = 0; fn < 4; ++fn) {
            int e = fn * 16 + r16;
            att[((size_t)b * LSEQ + l) * DMODEL + h * DHEAD + e] = f2bf(acc[fn][r] * inv);
        }
    }
}

// =====================================================================
extern "C" void kernel_launch(void* const* d_in, const int* in_sizes, int n_in,
                              void* d_out, int out_size, void* d_ws, size_t ws_size,
                              hipStream_t stream)
{
    const float* query = (const float*)d_in[0];
    const float* key_  = (const float*)d_in[1];
    const float* value = (const float*)d_in[2];
    const float* Wq = (const float*)d_in[3];
    const float* Wk = (const float*)d_in[4];
    const float* Wv = (const float*)d_in[5];
    const float* Wo = (const float*)d_in[6];
    float* out = (float*)d_out;

    const int BH = 2 * H_HEADS;  // 32

    // ws layout (bytes):
    //   [0,        8.4M)   Wb   : bf16 Wq|Wk|Wv|Wo
    //   [8.4M,    21.0M)   qp,kp,vp : bf16 [B,H,L,d]
    //   [21.0M,   25.2M)   attb : bf16 [M,1024]
    //   [25.2M,   37.75M)  Xb   : bf16 q|k|v (dead after proj)
    //   [25.2M,   33.55M)  St   : fp32 S^T chunk sums (alias Xb)
    //   [33.55M,  33.69M)  z    : fp32
    //   [33.69M,  37.88M)  stb  : bf16 S_prev^T pre-swizzled
    char* wsb = (char*)d_ws;
    unsigned short* Wb   = (unsigned short*)(wsb);
    unsigned short* qp   = (unsigned short*)(wsb + 8388608);
    unsigned short* kp   = (unsigned short*)(wsb + 12582912);
    unsigned short* vp   = (unsigned short*)(wsb + 16777216);
    unsigned short* attb = (unsigned short*)(wsb + 20971520);
    unsigned short* Xb   = (unsigned short*)(wsb + 25165824);
    float*          St   = (float*)(wsb + 25165824);
    float*          z    = (float*)(wsb + 33554432);
    unsigned short* stb  = (unsigned short*)(wsb + 33685504);

    dim3 blk(256);
    convert_kernel<<<dim3(2048, 7), blk, 0, stream>>>(
        query, key_, value, Wq, Wk, Wv, Wo, Xb, Wb);
    mfma_gemm64_kernel<true><<<dim3(768), blk, 0, stream>>>(
        Xb, Wb, qp, kp, vp, nullptr);
    chunk_kv_kernel<<<dim3(NCHUNK, BH), blk, 0, stream>>>(kp, vp, St, z);
    prefix_kernel<<<dim3(BH * 16), blk, 0, stream>>>(St, stb, z);
    attn_mfma_kernel<<<dim3(NCHUNK, BH), blk, 0, stream>>>(qp, kp, vp, stb, z, attb);
    mfma_gemm64_kernel<false><<<dim3(256), blk, 0, stream>>>(
        attb, Wb + 3 * (size_t)DMODEL * DMODEL, nullptr, nullptr, nullptr, out);
}

// Round 13
// 71.868 us; speedup vs baseline: 1.0707x; 1.0643x over previous
//
#include <hip/hip_runtime.h>
#include <hip/hip_bf16.h>
#include <math.h>

#define H_HEADS 16
#define DMODEL  1024
#define DHEAD   64
#define LSEQ    1024
#define CHUNK   64
#define NCHUNK  16
#define EPS_F   1e-6f

typedef __attribute__((ext_vector_type(8))) short bf16x8;   // 8 bf16 = 4 VGPRs
typedef __attribute__((ext_vector_type(4))) float f32x4;    // MFMA 16x16 accumulator

__device__ inline unsigned short f2bf(float f) {
    unsigned int u = __float_as_uint(f);
    u += 0x7FFF + ((u >> 16) & 1);          // round-to-nearest-even
    return (unsigned short)(u >> 16);
}
__device__ inline float bf2f(unsigned short h) {
    return __uint_as_float(((unsigned int)h) << 16);
}

// byte offset into a [64][64]-bf16 LDS tile (128B rows) with T2 XOR swizzle
__device__ inline int swz16(int row, int byteInRow) {
    return row * 128 + (byteInRow ^ ((row & 7) << 4));
}

// async global->LDS, 16B/lane. global src per-lane; LDS dst wave-uniform base.
#define GLOAD16(g, l) __builtin_amdgcn_global_load_lds( \
    (const __attribute__((address_space(1))) void*)(g), \
    (__attribute__((address_space(3))) void*)(l), 16, 0, 0)

// =====================================================================
// fp32 -> bf16 convert: q,k,v -> Xb[3][2M]; Wq,Wk,Wv,Wo -> Wb[4][1M].
// =====================================================================
__global__ __launch_bounds__(256)
void convert_kernel(const float* __restrict__ q, const float* __restrict__ k,
                    const float* __restrict__ v,
                    const float* __restrict__ Wq, const float* __restrict__ Wk,
                    const float* __restrict__ Wv, const float* __restrict__ Wo,
                    unsigned short* __restrict__ Xb, unsigned short* __restrict__ Wb)
{
    const int y = blockIdx.y;
    const float* src;
    unsigned short* dst;
    int n;
    if (y < 3) {
        src = (y == 0) ? q : (y == 1) ? k : v;
        dst = Xb + (size_t)y * (2 * LSEQ * DMODEL);
        n = 2 * LSEQ * DMODEL;
    } else {
        int w = y - 3;
        src = (w == 0) ? Wq : (w == 1) ? Wk : (w == 2) ? Wv : Wo;
        dst = Wb + (size_t)w * (DMODEL * DMODEL);
        n = DMODEL * DMODEL;
    }
    int idx = (blockIdx.x * 256 + threadIdx.x) * 4;
    if (idx < n) {
        float4 f = *(const float4*)(src + idx);
        ushort4 h = make_ushort4(f2bf(f.x), f2bf(f.y), f2bf(f.z), f2bf(f.w));
        *(ushort4*)(dst + idx) = h;
    }
}

// =====================================================================
// PROJ GEMM: BM=128, BN=128, BK=64, 512 thr = 8 waves (4x2 of 32x64),
// dbuf gload_lds staging (inverse-swizzled source, swizzled ds_read).
// grid (8,16,3). Each wave stages 16 rows (1024B) per operand subtile:
// wave base = wid*1024 (R12 bug: was wid*2048 -> half the rows undefined).
// =====================================================================
__global__ __launch_bounds__(512)
void proj_gemm_kernel(const unsigned short* __restrict__ Xb,
                      const unsigned short* __restrict__ Wb,
                      unsigned short* __restrict__ qp,
                      unsigned short* __restrict__ kp,
                      unsigned short* __restrict__ vp)
{
    const int z = blockIdx.z;
    const unsigned short* A = Xb + (size_t)z * (2 * LSEQ * DMODEL);
    const unsigned short* W = Wb + (size_t)z * (DMODEL * DMODEL);

    __shared__ char AsB[2][16384];    // [dbuf][2 subtiles x 128 rows x 64B]
    __shared__ char BsB[2][16384];

    const int tid  = threadIdx.x;
    const int m0   = blockIdx.y * 128;
    const int n0   = blockIdx.x * 128;
    const int lane = tid & 63;
    const int wid  = tid >> 6;               // 0..7
    const int wm   = (wid & 3) * 32;
    const int wn   = (wid >> 2) * 64;
    const int r16  = lane & 15;
    const int qh   = lane >> 4;

    // staging: thread owns row tid>>2 (0..127), slot (tid&3).
    // wave wid covers rows wid*16..wid*16+15 -> LDS base wid*1024 (linear).
    const int row = tid >> 2;
    const int sw  = ((lane & 3) ^ ((lane >> 3) & 3)) * 16;   // inverse slot swz
    const char* srcA = (const char*)(A + (size_t)(m0 + row) * DMODEL) + sw;
    const char* srcB = (const char*)(W + (size_t)(n0 + row) * DMODEL) + sw;

    const int sl = (qh ^ ((r16 >> 1) & 3)) * 8;   // swizzled ds_read slot

    f32x4 acc[2][4];
#pragma unroll
    for (int i = 0; i < 2; ++i)
#pragma unroll
        for (int j = 0; j < 4; ++j) acc[i][j] = (f32x4)0.0f;

    auto STAGE = [&](int buf, int kt) {
#pragma unroll
        for (int hh = 0; hh < 2; ++hh) {
            size_t go = (size_t)(kt + hh * 32) * 2;
            GLOAD16(srcA + go, AsB[buf] + hh * 8192 + wid * 1024);
            GLOAD16(srcB + go, BsB[buf] + hh * 8192 + wid * 1024);
        }
    };
    auto COMPUTE = [&](int buf) {
        bf16x8 af[2][2], bg[2][4];
#pragma unroll
        for (int hh = 0; hh < 2; ++hh) {
#pragma unroll
            for (int fm = 0; fm < 2; ++fm)
                af[hh][fm] = *(const bf16x8*)(AsB[buf] + hh * 8192 +
                                 ((wm + fm * 16 + r16) * 32 + sl) * 2);
#pragma unroll
            for (int fn = 0; fn < 4; ++fn)
                bg[hh][fn] = *(const bf16x8*)(BsB[buf] + hh * 8192 +
                                 ((wn + fn * 16 + r16) * 32 + sl) * 2);
        }
#pragma unroll
        for (int hh = 0; hh < 2; ++hh)
#pragma unroll
            for (int fm = 0; fm < 2; ++fm)
#pragma unroll
                for (int fn = 0; fn < 4; ++fn)
                    acc[fm][fn] = __builtin_amdgcn_mfma_f32_16x16x32_bf16(
                        af[hh][fm], bg[hh][fn], acc[fm][fn], 0, 0, 0);
    };

    STAGE(0, 0);
    asm volatile("s_waitcnt vmcnt(0)" ::: "memory");
    __builtin_amdgcn_s_barrier();

    int cur = 0;
#pragma unroll 1
    for (int t = 0; t < (DMODEL / 64) - 1; ++t) {
        STAGE(cur ^ 1, (t + 1) * 64);
        __builtin_amdgcn_sched_barrier(0);
        COMPUTE(cur);
        asm volatile("s_waitcnt vmcnt(0) lgkmcnt(0)" ::: "memory");
        __builtin_amdgcn_sched_barrier(0);
        __builtin_amdgcn_s_barrier();
        cur ^= 1;
    }
    COMPUTE(cur);

    unsigned short* O = (z == 0) ? qp : (z == 1) ? kp : vp;
    const float sc = (z < 2) ? 0.125f : 1.f;
#pragma unroll
    for (int fm = 0; fm < 2; ++fm) {
#pragma unroll
        for (int r = 0; r < 4; ++r) {
            int m = m0 + wm + fm * 16 + qh * 4 + r;
            int b = m >> 10, l = m & 1023;
#pragma unroll
            for (int fn = 0; fn < 4; ++fn) {
                int n = n0 + wn + fn * 16 + r16;
                int h = n >> 6, e = n & 63;
                float y = acc[fm][fn][r] * sc;
                if (z < 2) y = (y > 0.f) ? y + 1.f : __expf(y);
                O[(((size_t)(b * H_HEADS + h)) * LSEQ + l) * DHEAD + e] = f2bf(y);
            }
        }
    }
}

// =====================================================================
// OUT GEMM: BM=64, BN=128, BK=64, 256 thr (R9 structure, 3D grid (8,32)).
// =====================================================================
__global__ __launch_bounds__(256)
void out_gemm_kernel(const unsigned short* __restrict__ Ab,
                     const unsigned short* __restrict__ W,
                     float* __restrict__ outf)
{
    __shared__ char AsB[2][8192];
    __shared__ char BsB[2][16384];

    const int tid  = threadIdx.x;
    const int m0   = blockIdx.y * 64;
    const int n0   = blockIdx.x * 128;
    const int lane = tid & 63;
    const int wid  = tid >> 6;
    const int wm   = (wid >> 1) * 32;
    const int wn   = (wid & 1) * 64;
    const int r16  = lane & 15;
    const int qh   = lane >> 4;

    const int rA  = wid * 16 + (lane >> 2);
    const int rB0 = wid * 32 + (lane >> 2);
    const int sw  = ((lane & 3) ^ ((lane >> 3) & 3)) * 16;
    const char* srcA  = (const char*)(Ab + (size_t)(m0 + rA)  * DMODEL) + sw;
    const char* srcB0 = (const char*)(W + (size_t)(n0 + rB0) * DMODEL) + sw;
    const char* srcB1 = (const char*)(W + (size_t)(n0 + rB0 + 16) * DMODEL) + sw;

    const int sl = (qh ^ ((r16 >> 1) & 3)) * 8;

    f32x4 acc[2][4];
#pragma unroll
    for (int i = 0; i < 2; ++i)
#pragma unroll
        for (int j = 0; j < 4; ++j) acc[i][j] = (f32x4)0.0f;

    auto STAGE = [&](int buf, int kt) {
#pragma unroll
        for (int hh = 0; hh < 2; ++hh) {
            size_t go = (size_t)(kt + hh * 32) * 2;
            GLOAD16(srcA  + go, AsB[buf] + wid * 1024 + hh * 4096);
            GLOAD16(srcB0 + go, BsB[buf] + wid * 2048 + hh * 8192);
            GLOAD16(srcB1 + go, BsB[buf] + wid * 2048 + 1024 + hh * 8192);
        }
    };
    auto COMPUTE = [&](int buf) {
        bf16x8 af[2][2], bg[2][4];
#pragma unroll
        for (int hh = 0; hh < 2; ++hh) {
#pragma unroll
            for (int fm = 0; fm < 2; ++fm)
                af[hh][fm] = *(const bf16x8*)(AsB[buf] + hh * 4096 +
                                 ((wm + fm * 16 + r16) * 32 + sl) * 2);
#pragma unroll
            for (int fn = 0; fn < 4; ++fn)
                bg[hh][fn] = *(const bf16x8*)(BsB[buf] + hh * 8192 +
                                 ((wn + fn * 16 + r16) * 32 + sl) * 2);
        }
#pragma unroll
        for (int hh = 0; hh < 2; ++hh)
#pragma unroll
            for (int fm = 0; fm < 2; ++fm)
#pragma unroll
                for (int fn = 0; fn < 4; ++fn)
                    acc[fm][fn] = __builtin_amdgcn_mfma_f32_16x16x32_bf16(
                        af[hh][fm], bg[hh][fn], acc[fm][fn], 0, 0, 0);
    };

    STAGE(0, 0);
    asm volatile("s_waitcnt vmcnt(0)" ::: "memory");
    __builtin_amdgcn_s_barrier();

    int cur = 0;
#pragma unroll 1
    for (int t = 0; t < (DMODEL / 64) - 1; ++t) {
        STAGE(cur ^ 1, (t + 1) * 64);
        __builtin_amdgcn_sched_barrier(0);
        COMPUTE(cur);
        asm volatile("s_waitcnt vmcnt(0) lgkmcnt(0)" ::: "memory");
        __builtin_amdgcn_sched_barrier(0);
        __builtin_amdgcn_s_barrier();
        cur ^= 1;
    }
    COMPUTE(cur);

#pragma unroll
    for (int fm = 0; fm < 2; ++fm) {
#pragma unroll
        for (int r = 0; r < 4; ++r) {
            int m = m0 + wm + fm * 16 + qh * 4 + r;
#pragma unroll
            for (int fn = 0; fn < 4; ++fn) {
                int n = n0 + wn + fn * 16 + r16;
                outf[(size_t)m * DMODEL + n] = acc[fm][fn][r];
            }
        }
    }
}

// =====================================================================
// chunk KV sums via MFMA: St_c[e][i] = sum_s V[s][e]*K[s][i]  (fp32 out),
// z_c[i] = sum_s K[s][i] via ones-row MFMA on wave 0.
// =====================================================================
__global__ __launch_bounds__(256)
void chunk_kv_kernel(const unsigned short* __restrict__ kp,
                     const unsigned short* __restrict__ vp,
                     float* __restrict__ St, float* __restrict__ z)
{
    const int c = blockIdx.x, bh = blockIdx.y;
    const int tid = threadIdx.x;
    const int lane = tid & 63;
    const int w = tid >> 6;
    const int r16 = lane & 15, qh = lane >> 4;

    __shared__ unsigned short kT[64 * 64];   // K^T[i][s], swizzled
    __shared__ unsigned short vt[64 * 64];   // V^T[e][s], swizzled

    const size_t base = ((size_t)bh * LSEQ + (size_t)c * CHUNK) * DHEAD;

#pragma unroll
    for (int i = 0; i < 2; ++i) {
        int id  = tid + i * 256;
        int row = id >> 3;          // s
        int cg  = (id & 7) * 8;     // d/e octet
        bf16x8 kv = *(const bf16x8*)(kp + base + row * 64 + cg);
        bf16x8 vv = *(const bf16x8*)(vp + base + row * 64 + cg);
#pragma unroll
        for (int j = 0; j < 8; ++j) {
            *(unsigned short*)((char*)kT + swz16(cg + j, row * 2)) = (unsigned short)kv[j];
            *(unsigned short*)((char*)vt + swz16(cg + j, row * 2)) = (unsigned short)vv[j];
        }
    }
    __syncthreads();

    bf16x8 av[2], bK[2][4];
#pragma unroll
    for (int kk = 0; kk < 2; ++kk) {
        av[kk] = *(const bf16x8*)((char*)vt + swz16(w * 16 + r16, kk * 64 + qh * 16));
#pragma unroll
        for (int fn = 0; fn < 4; ++fn)
            bK[kk][fn] = *(const bf16x8*)((char*)kT + swz16(fn * 16 + r16, kk * 64 + qh * 16));
    }

    f32x4 acc[4];
#pragma unroll
    for (int fn = 0; fn < 4; ++fn) acc[fn] = (f32x4)0.0f;
#pragma unroll
    for (int kk = 0; kk < 2; ++kk)
#pragma unroll
        for (int fn = 0; fn < 4; ++fn)
            acc[fn] = __builtin_amdgcn_mfma_f32_16x16x32_bf16(av[kk], bK[kk][fn], acc[fn], 0, 0, 0);

    const size_t sbase = ((size_t)bh * NCHUNK + c) * (DHEAD * DHEAD);
#pragma unroll
    for (int r = 0; r < 4; ++r) {
        int e = w * 16 + qh * 4 + r;
#pragma unroll
        for (int fn = 0; fn < 4; ++fn)
            St[sbase + (size_t)e * 64 + fn * 16 + r16] = acc[fn][r];
    }

    if (w == 0) {   // z via ones-row MFMA (A = all 1.0 bf16, exact)
        bf16x8 ones;
#pragma unroll
        for (int j = 0; j < 8; ++j) ones[j] = (short)0x3F80;
        f32x4 accz[4];
#pragma unroll
        for (int fn = 0; fn < 4; ++fn) accz[fn] = (f32x4)0.0f;
#pragma unroll
        for (int kk = 0; kk < 2; ++kk)
#pragma unroll
            for (int fn = 0; fn < 4; ++fn)
                accz[fn] = __builtin_amdgcn_mfma_f32_16x16x32_bf16(ones, bK[kk][fn], accz[fn], 0, 0, 0);
        if (qh == 0) {
            const size_t zb = ((size_t)bh * NCHUNK + c) * 64;
#pragma unroll
            for (int fn = 0; fn < 4; ++fn)
                z[zb + fn * 16 + r16] = accz[fn][0];
        }
    }
}

// =====================================================================
// Exclusive prefix over chunks: St fp32 -> stb bf16 (pre-swizzled rows so
// attn can global_load_lds linearly); z scanned fp32 in place.
// =====================================================================
__global__ __launch_bounds__(256)
void prefix_kernel(const float* __restrict__ St, unsigned short* __restrict__ stb,
                   float* __restrict__ z)
{
    const int bh   = blockIdx.x >> 4;
    const int eblk = blockIdx.x & 15;
    const int idx  = eblk * 256 + threadIdx.x;   // 0..4095
    const int e = idx >> 6, i = idx & 63;

    const size_t ibase = (size_t)bh * NCHUNK * 4096 + idx;
    float v[NCHUNK];
#pragma unroll
    for (int c = 0; c < NCHUNK; ++c)
        v[c] = St[ibase + (size_t)c * 4096];

    const size_t obase = (size_t)bh * NCHUNK * 4096 + e * 64 + (i ^ ((e & 7) << 3));
    float run = 0.f;
#pragma unroll
    for (int c = 0; c < NCHUNK; ++c) {
        stb[obase + (size_t)c * 4096] = f2bf(run);
        run += v[c];
    }

    if (eblk == 0 && threadIdx.x < DHEAD) {
        const size_t zb = (size_t)bh * NCHUNK * DHEAD + threadIdx.x;
        float zv[NCHUNK];
#pragma unroll
        for (int c = 0; c < NCHUNK; ++c)
            zv[c] = z[zb + (size_t)c * DHEAD];
        float zr = 0.f;
#pragma unroll
        for (int c = 0; c < NCHUNK; ++c) {
            z[zb + (size_t)c * DHEAD] = zr;
            zr += zv[c];
        }
    }
}

// =====================================================================
// Per-chunk causal attention, full MFMA:
//   P = Qp@Kp^T (mask, rowsum in C-regs) ; O = Qp@Sprev^T + P@V^T.
//   den = qp.z_prev (pre-pass) + rowsum.  grid = (NC, BH), 256 thr.
// =====================================================================
__global__ __launch_bounds__(256)
void attn_mfma_kernel(const unsigned short* __restrict__ qp,
                      const unsigned short* __restrict__ kp,
                      const unsigned short* __restrict__ vp,
                      const unsigned short* __restrict__ stb,
                      const float* __restrict__ zpre,
                      unsigned short* __restrict__ att)
{
    const int c = blockIdx.x, bh = blockIdx.y;
    const int b = bh >> 4, h = bh & 15;
    const int tid = threadIdx.x;
    const int lane = tid & 63;
    const int w = tid >> 6;
    const int r16 = lane & 15, qh = lane >> 4;

    __shared__ unsigned short qs[64 * 64];   // Qp[t][d] swizzled
    __shared__ unsigned short ks[64 * 64];   // Kp[s][d] swizzled
    __shared__ unsigned short vt[64 * 64];   // V^T[e][s] swizzled
    __shared__ unsigned short stl[64 * 64];  // Sprev^T[e][i] (global pre-swizzled)
    __shared__ unsigned short ps[64 * 64];   // masked P[t][s] swizzled
    __shared__ float denl[64];

    const size_t base = ((size_t)bh * LSEQ + (size_t)c * CHUNK) * DHEAD;
    const unsigned short* stg = stb + ((size_t)bh * NCHUNK + c) * 4096;
    const float* zp = zpre + ((size_t)bh * NCHUNK + c) * 64;

    // stage Sprev^T via gload (global rows pre-swizzled by prefix_kernel)
    {
        const char* src = (const char*)stg + w * 2048 + lane * 16;
        GLOAD16(src,        (char*)stl + w * 2048);
        GLOAD16(src + 1024, (char*)stl + w * 2048 + 1024);
    }
    // stage Qp, Kp natural; V transposed
#pragma unroll
    for (int i = 0; i < 2; ++i) {
        int id  = tid + i * 256;
        int row = id >> 3;
        int cg  = (id & 7) * 8;
        bf16x8 qv = *(const bf16x8*)(qp + base + row * 64 + cg);
        bf16x8 kv = *(const bf16x8*)(kp + base + row * 64 + cg);
        *(bf16x8*)((char*)qs + swz16(row, cg * 2)) = qv;
        *(bf16x8*)((char*)ks + swz16(row, cg * 2)) = kv;
        bf16x8 vv = *(const bf16x8*)(vp + base + row * 64 + cg);
#pragma unroll
        for (int j = 0; j < 8; ++j)
            *(unsigned short*)((char*)vt + swz16(cg + j, row * 2)) = (unsigned short)vv[j];
    }
    // den1[t] = qp_row_t . z_prev  (4 lanes per row)
    {
        int t = tid >> 2, kq = tid & 3;
        const unsigned short* qrow = qp + base + t * 64 + kq * 16;
        bf16x8 a0 = *(const bf16x8*)(qrow);
        bf16x8 a1 = *(const bf16x8*)(qrow + 8);
        float s = 0.f;
#pragma unroll
        for (int j = 0; j < 8; ++j) {
            s = fmaf(bf2f((unsigned short)a0[j]), zp[kq * 16 + j], s);
            s = fmaf(bf2f((unsigned short)a1[j]), zp[kq * 16 + 8 + j], s);
        }
        s += __shfl_xor(s, 1);
        s += __shfl_xor(s, 2);
        if (kq == 0) denl[t] = s;
    }
    __syncthreads();   // drains gload (vmcnt) + all LDS staging

    // A-frags of Qp for wave's 16-row slice (shared by P and O1)
    bf16x8 aq[2];
#pragma unroll
    for (int kk = 0; kk < 2; ++kk)
        aq[kk] = *(const bf16x8*)((char*)qs + swz16(w * 16 + r16, kk * 64 + qh * 16));

    // ---- P = Qp @ Kp^T ----
    f32x4 accp[4];
#pragma unroll
    for (int fn = 0; fn < 4; ++fn) accp[fn] = (f32x4)0.0f;
#pragma unroll
    for (int kk = 0; kk < 2; ++kk)
#pragma unroll
        for (int fn = 0; fn < 4; ++fn) {
            bf16x8 bk = *(const bf16x8*)((char*)ks + swz16(fn * 16 + r16, kk * 64 + qh * 16));
            accp[fn] = __builtin_amdgcn_mfma_f32_16x16x32_bf16(aq[kk], bk, accp[fn], 0, 0, 0);
        }

    // mask (causal within chunk), rowsum, write bf16 P to LDS
    float rs[4];
#pragma unroll
    for (int r = 0; r < 4; ++r) {
        int t_loc = w * 16 + qh * 4 + r;
        float rsum = 0.f;
#pragma unroll
        for (int fn = 0; fn < 4; ++fn) {
            int s_loc = fn * 16 + r16;
            float p = (s_loc <= t_loc) ? accp[fn][r] : 0.f;
            rsum += p;
            *(unsigned short*)((char*)ps + swz16(t_loc, s_loc * 2)) = f2bf(p);
        }
        rsum += __shfl_xor(rsum, 1);
        rsum += __shfl_xor(rsum, 2);
        rsum += __shfl_xor(rsum, 4);
        rsum += __shfl_xor(rsum, 8);
        rs[r] = rsum;
    }

    // ---- O = Qp @ Sprev^T + P @ V^T ----
    f32x4 acc[4];
#pragma unroll
    for (int fn = 0; fn < 4; ++fn) acc[fn] = (f32x4)0.0f;
#pragma unroll
    for (int kk = 0; kk < 2; ++kk)
#pragma unroll
        for (int fn = 0; fn < 4; ++fn) {
            bf16x8 bs = *(const bf16x8*)((char*)stl + swz16(fn * 16 + r16, kk * 64 + qh * 16));
            acc[fn] = __builtin_amdgcn_mfma_f32_16x16x32_bf16(aq[kk], bs, acc[fn], 0, 0, 0);
        }
    bf16x8 ap[2];
#pragma unroll
    for (int kk = 0; kk < 2; ++kk)
        ap[kk] = *(const bf16x8*)((char*)ps + swz16(w * 16 + r16, kk * 64 + qh * 16));
#pragma unroll
    for (int kk = 0; kk < 2; ++kk)
#pragma unroll
        for (int fn = 0; fn < 4; ++fn) {
            bf16x8 bv = *(const bf16x8*)((char*)vt + swz16(fn * 16 + r16, kk * 64 + qh * 16));
            acc[fn] = __builtin_amdgcn_mfma_f32_16x16x32_bf16(ap[kk], bv, acc[fn], 0, 0, 0);
        }

    // epilogue: divide by den, store bf16 att [B, L, D]
#pragma unroll
    for (int r = 0; r < 4; ++r) {
        int t_loc = w * 16 + qh * 4 + r;
        int l = c * CHUNK + t_loc;
        float inv = 1.f / (denl[t_loc] + rs[r] + EPS_F);
#pragma unroll
        for (int fn = 0; fn < 4; ++fn) {
            int e = fn * 16 + r16;
            att[((size_t)b * LSEQ + l) * DMODEL + h * DHEAD + e] = f2bf(acc[fn][r] * inv);
        }
    }
}

// =====================================================================
extern "C" void kernel_launch(void* const* d_in, const int* in_sizes, int n_in,
                              void* d_out, int out_size, void* d_ws, size_t ws_size,
                              hipStream_t stream)
{
    const float* query = (const float*)d_in[0];
    const float* key_  = (const float*)d_in[1];
    const float* value = (const float*)d_in[2];
    const float* Wq = (const float*)d_in[3];
    const float* Wk = (const float*)d_in[4];
    const float* Wv = (const float*)d_in[5];
    const float* Wo = (const float*)d_in[6];
    float* out = (float*)d_out;

    const int M  = 2 * LSEQ;     // 2048
    const int BH = 2 * H_HEADS;  // 32

    // ws layout (bytes):
    //   [0,        8.4M)   Wb   : bf16 Wq|Wk|Wv|Wo
    //   [8.4M,    21.0M)   qp,kp,vp : bf16 [B,H,L,d]
    //   [21.0M,   25.2M)   attb : bf16 [M,1024]
    //   [25.2M,   37.75M)  Xb   : bf16 q|k|v (dead after proj)
    //   [25.2M,   33.55M)  St   : fp32 S^T chunk sums (alias Xb)
    //   [33.55M,  33.69M)  z    : fp32
    //   [33.69M,  37.88M)  stb  : bf16 S_prev^T pre-swizzled
    char* wsb = (char*)d_ws;
    unsigned short* Wb   = (unsigned short*)(wsb);
    unsigned short* qp   = (unsigned short*)(wsb + 8388608);
    unsigned short* kp   = (unsigned short*)(wsb + 12582912);
    unsigned short* vp   = (unsigned short*)(wsb + 16777216);
    unsigned short* attb = (unsigned short*)(wsb + 20971520);
    unsigned short* Xb   = (unsigned short*)(wsb + 25165824);
    float*          St   = (float*)(wsb + 25165824);
    float*          z    = (float*)(wsb + 33554432);
    unsigned short* stb  = (unsigned short*)(wsb + 33685504);

    dim3 blk(256);
    convert_kernel<<<dim3(2048, 7), blk, 0, stream>>>(
        query, key_, value, Wq, Wk, Wv, Wo, Xb, Wb);
    proj_gemm_kernel<<<dim3(DMODEL / 128, M / 128, 3), dim3(512), 0, stream>>>(
        Xb, Wb, qp, kp, vp);
    chunk_kv_kernel<<<dim3(NCHUNK, BH), blk, 0, stream>>>(kp, vp, St, z);
    prefix_kernel<<<dim3(BH * 16), blk, 0, stream>>>(St, stb, z);
    attn_mfma_kernel<<<dim3(NCHUNK, BH), blk, 0, stream>>>(qp, kp, vp, stb, z, attb);
    out_gemm_kernel<<<dim3(DMODEL / 128, M / 64), blk, 0, stream>>>(
        attb, Wb + 3 * (size_t)DMODEL * DMODEL, out);
}